// Round 1
// baseline (2897.270 us; speedup 1.0000x reference)
//
#include <hip/hip_runtime.h>

#define Bv 2
#define Cv 768
#define Hv 256
#define Wv 256
#define WHv 129
#define NBv 8
#define BSv 96

typedef float2 cplx;

__device__ __forceinline__ unsigned brev8(unsigned v) { return __brev(v) >> 24; }

// Each wave fills the whole table itself -> no cross-wave dependency, no barrier.
__device__ __forceinline__ void fill_tw(cplx* tw, int lane) {
#pragma unroll
  for (int r = 0; r < 4; ++r) {
    int m = lane + (r << 6);
    float s, c;
    __sincosf((float)m * (-6.283185307179586f / 256.0f), &s, &c);
    tw[m] = make_float2(c, s);  // e^{-2*pi*i*m/256}
  }
}

// In-place radix-2 DIT 256-pt FFT on one LDS row, executed by one 64-lane wave.
// Input must be scattered in bit-reversed order. Output in natural order.
// Wave-synchronous: same-wave LDS ops complete in order; no barriers needed.
template <int INV>
__device__ __forceinline__ void fft256(cplx* row, const cplx* tw, int lane) {
#pragma unroll
  for (int len = 2; len <= 256; len <<= 1) {
    const int half = len >> 1;
#pragma unroll
    for (int r = 0; r < 2; ++r) {
      int b = lane + (r << 6);      // butterfly id 0..127
      int j = b & (half - 1);
      int i0 = 2 * b - j;           // = (b/half)*len + j
      int i1 = i0 + half;
      cplx u = row[i0];
      cplx v = row[i1];
      cplx w = tw[j * (256 / len)];
      float wy = INV ? -w.y : w.y;
      float vr = v.x * w.x - v.y * wy;
      float vi = v.x * wy + v.y * w.x;
      row[i0] = make_float2(u.x + vr, u.y + vi);
      row[i1] = make_float2(u.x - vr, u.y - vi);
    }
  }
}

// K1: row rfft (real 256 -> 129 complex), write transposed F[b,c,w,h].
__global__ __launch_bounds__(512) void k_fwd_row(const float* __restrict__ x,
                                                 cplx* __restrict__ F) {
  __shared__ cplx buf[8][257];
  __shared__ cplx tw[256];
  int tid = threadIdx.x;
  int wv = tid >> 6, lane = tid & 63;
  fill_tw(tw, lane);
  int r0 = blockIdx.x * 8;
  int bc = r0 >> 8;      // image index (b*C + c)
  int h0 = r0 & 255;     // first row in this block
  const float* xr = x + ((size_t)bc * 256 + (size_t)(h0 + wv)) * 256;
#pragma unroll
  for (int r = 0; r < 4; ++r) {
    int idx = lane + (r << 6);
    buf[wv][brev8(idx)] = make_float2(xr[idx], 0.0f);
  }
  fft256<0>(&buf[wv][0], tw, lane);
  __syncthreads();  // cross-wave transposed write below
  for (int e = tid; e < WHv * 8; e += 512) {
    int w = e >> 3, hh = e & 7;
    F[((size_t)bc * WHv + w) * 256 + h0 + hh] = buf[hh][w];
  }
}

// K2/K4: in-place complex FFT along H (columns are contiguous in F layout).
template <int INV>
__global__ __launch_bounds__(512) void k_col_fft(cplx* __restrict__ F) {
  __shared__ cplx buf[8][256];
  __shared__ cplx tw[256];
  int tid = threadIdx.x;
  int wv = tid >> 6, lane = tid & 63;
  fill_tw(tw, lane);
  size_t base = ((size_t)blockIdx.x * 8 + wv) * 256;
#pragma unroll
  for (int r = 0; r < 4; ++r) {
    int idx = lane + (r << 6);
    buf[wv][brev8(idx)] = F[base + idx];
  }
  fft256<INV>(&buf[wv][0], tw, lane);
#pragma unroll
  for (int r = 0; r < 4; ++r) {
    int idx = lane + (r << 6);
    F[base + idx] = buf[wv][idx];
  }
}

// K3: per-mode block-diagonal complex MLP, in place on F.
// block = 256 threads = 4 waves; wave y computes outputs o = y*24 .. y*24+23
// for 64 consecutive h (lane = h). Weights via wave-uniform pointer -> s_load.
__global__ __launch_bounds__(256) void k_mix(cplx* __restrict__ F,
                                             const float* __restrict__ w1,
                                             const float* __restrict__ b1,
                                             const float* __restrict__ w2,
                                             const float* __restrict__ b2) {
  __shared__ cplx T[BSv * 64];  // 48 KB
  int bid = blockIdx.x;
  int ht = bid & 3; bid >>= 2;
  int w = bid % WHv; bid /= WHv;
  int k = bid & 7;
  int b = bid >> 3;
  int tid = threadIdx.x;
  int hx = tid & 63;
  int y = __builtin_amdgcn_readfirstlane(tid >> 6);
  int h0 = ht << 6;
  size_t base = ((size_t)(b * Cv + k * BSv) * WHv + w) * 256 + h0;
  const size_t cstride = (size_t)WHv * 256;

  // Load A tile (96 channels x 64 h), fold in forward ortho scale 1/256.
  for (int e = tid; e < BSv * 64; e += 256) {
    int i = e >> 6, hh = e & 63;
    cplx v = F[base + (size_t)i * cstride + hh];
    T[e] = make_float2(v.x * (1.0f / 256.0f), v.y * (1.0f / 256.0f));
  }
  __syncthreads();

  float accr[24], acci[24];
#pragma unroll
  for (int j = 0; j < 24; ++j) { accr[j] = 0.0f; acci[j] = 0.0f; }
  const cplx* W1 = (const cplx*)w1 + (size_t)k * BSv * BSv;
  for (int i = 0; i < BSv; ++i) {
    cplx a = T[(i << 6) + hx];
    const cplx* wr = W1 + i * BSv + y * 24;
#pragma unroll
    for (int j = 0; j < 24; ++j) {
      cplx wv = wr[j];
      accr[j] = fmaf(a.x, wv.x, fmaf(-a.y, wv.y, accr[j]));
      acci[j] = fmaf(a.x, wv.y, fmaf(a.y, wv.x, acci[j]));
    }
  }
  __syncthreads();  // everyone done reading A tile
  const cplx* B1 = (const cplx*)b1 + k * BSv + y * 24;
#pragma unroll
  for (int j = 0; j < 24; ++j) {
    cplx bb = B1[j];
    T[((y * 24 + j) << 6) + hx] =
        make_float2(fmaxf(accr[j] + bb.x, 0.0f), fmaxf(acci[j] + bb.y, 0.0f));
  }
  __syncthreads();  // o1 visible to all

#pragma unroll
  for (int j = 0; j < 24; ++j) { accr[j] = 0.0f; acci[j] = 0.0f; }
  const cplx* W2 = (const cplx*)w2 + (size_t)k * BSv * BSv;
  for (int i = 0; i < BSv; ++i) {
    cplx a = T[(i << 6) + hx];
    const cplx* wr = W2 + i * BSv + y * 24;
#pragma unroll
    for (int j = 0; j < 24; ++j) {
      cplx wv = wr[j];
      accr[j] = fmaf(a.x, wv.x, fmaf(-a.y, wv.y, accr[j]));
      acci[j] = fmaf(a.x, wv.y, fmaf(a.y, wv.x, acci[j]));
    }
  }
  const cplx* B2 = (const cplx*)b2 + k * BSv + y * 24;
#pragma unroll
  for (int j = 0; j < 24; ++j) {
    cplx bb = B2[j];
    float re = accr[j] + bb.x;
    float im = acci[j] + bb.y;
    re = copysignf(fmaxf(fabsf(re) - 0.01f, 0.0f), re);  // softshrink
    im = copysignf(fmaxf(fabsf(im) - 0.01f, 0.0f), im);
    F[base + (size_t)(y * 24 + j) * cstride + hx] = make_float2(re, im);
  }
}

// K5: Hermitian-extend along w, inverse FFT, real part * 1/256 + residual.
__global__ __launch_bounds__(512) void k_inv_row(const cplx* __restrict__ F,
                                                 const float* __restrict__ x,
                                                 float* __restrict__ out) {
  __shared__ cplx buf[8][257];
  __shared__ cplx tw[256];
  int tid = threadIdx.x;
  int wv = tid >> 6, lane = tid & 63;
  fill_tw(tw, lane);
  int r0 = blockIdx.x * 8;
  int bc = r0 >> 8;
  int h0 = r0 & 255;
  // gather spectrum tile [129 w][8 h], scatter bit-reversed + Hermitian mirror
  for (int e = tid; e < WHv * 8; e += 512) {
    int w = e >> 3, hh = e & 7;
    cplx v = F[((size_t)bc * WHv + w) * 256 + h0 + hh];
    buf[hh][brev8(w)] = v;
    if (w >= 1 && w <= 127) buf[hh][brev8(256 - w)] = make_float2(v.x, -v.y);
  }
  __syncthreads();
  fft256<1>(&buf[wv][0], tw, lane);
  __syncthreads();
  for (int e = tid; e < 8 * 256; e += 512) {
    int n = e & 255, hh = e >> 8;
    size_t o = ((size_t)bc * 256 + h0 + hh) * 256 + n;
    out[o] = buf[hh][n].x * (1.0f / 256.0f) + x[o];
  }
}

extern "C" void kernel_launch(void* const* d_in, const int* in_sizes, int n_in,
                              void* d_out, int out_size, void* d_ws, size_t ws_size,
                              hipStream_t stream) {
  const float* x  = (const float*)d_in[0];
  const float* w1 = (const float*)d_in[1];
  const float* b1 = (const float*)d_in[2];
  const float* w2 = (const float*)d_in[3];
  const float* b2 = (const float*)d_in[4];
  float* out = (float*)d_out;
  cplx* F = (cplx*)d_ws;  // (B, C, Wh, H) complex fp32 = ~406 MB

  k_fwd_row<<<Bv * Cv * Hv / 8, 512, 0, stream>>>(x, F);
  k_col_fft<0><<<Bv * Cv * WHv / 8, 512, 0, stream>>>(F);
  k_mix<<<Bv * NBv * WHv * (Hv / 64), 256, 0, stream>>>(F, w1, b1, w2, b2);
  k_col_fft<1><<<Bv * Cv * WHv / 8, 512, 0, stream>>>(F);
  k_inv_row<<<Bv * Cv * Hv / 8, 512, 0, stream>>>(F, x, out);
}